// Round 6
// baseline (780.973 us; speedup 1.0000x reference)
//
#include <hip/hip_runtime.h>

#define N_NODES 20000
#define N_EDGES 320000
#define N_GRAPH 256

// ------------------------- templated tiled fp32 GEMM -------------------------
// zstride==0: direct C = op(A@B + bias). zstride>0 (split-K): block z plain-stores
// its partial to C + z*zstride (summed later by bias_sum_kernel).
// A-tile k-major in LDS; B-fragment split in two stride-4 groups (2-way = free).
// 2-deep LDS double buffer + register prefetch: ONE __syncthreads per K-tile.
template<int BM, int BN, int TM, int TN>
__launch_bounds__(256)
__global__ void gemm_t(const float* __restrict__ A, int lda,
                       const float* __restrict__ B, int ldb,
                       float* __restrict__ C, int ldc, int zstride,
                       const float* __restrict__ bias,
                       int Nr, int K, int M, int do_relu, int kchunk) {
  constexpr int BK = 16;
  constexpr int LDA = BM + 4;
  __shared__ __align__(16) float As[2][BK][LDA];
  __shared__ __align__(16) float Bs[2][BK][BN];
  const int tid = threadIdx.x;
  const int row0 = blockIdx.y * BM, col0 = blockIdx.x * BN;
  constexpr int NX = BN / TN;
  const int tx = tid % NX, ty = tid / NX;
  float acc[TM][TN] = {};
  const int klo = blockIdx.z * kchunk;
  const int khi = min(klo + kchunk, K);
  const int nt = (khi - klo + BK - 1) / BK;

  constexpr int AIT = BM * BK / 4 / 256;
  constexpr int BIT = BK * BN / 4 / 256;
  float4 pa[AIT], pb[BIT];

  auto load_tile = [&](int k0) {
#pragma unroll
    for (int it = 0; it < AIT; ++it) {
      const int s = it * 256 + tid;
      const int row = s >> 2, kq = (s & 3) << 2;
      float4 av = make_float4(0.f, 0.f, 0.f, 0.f);
      const int gr = row0 + row, gk = k0 + kq;
      if (gr < Nr) {
        const float* Ap = A + (size_t)gr * lda + gk;
        if (gk + 3 < khi) { av.x = Ap[0]; av.y = Ap[1]; av.z = Ap[2]; av.w = Ap[3]; }
        else {
          if (gk     < khi) av.x = Ap[0];
          if (gk + 1 < khi) av.y = Ap[1];
          if (gk + 2 < khi) av.z = Ap[2];
        }
      }
      pa[it] = av;
    }
#pragma unroll
    for (int it = 0; it < BIT; ++it) {
      const int s = it * 256 + tid;
      const int kr = s / (BN / 4), c = (s % (BN / 4)) << 2;
      float4 bv = make_float4(0.f, 0.f, 0.f, 0.f);
      const int gk = k0 + kr, gc = col0 + c;
      if (gk < khi) {
        const float* Bp = B + (size_t)gk * ldb + gc;
        if (gc + 3 < M) { bv.x = Bp[0]; bv.y = Bp[1]; bv.z = Bp[2]; bv.w = Bp[3]; }
        else {
          if (gc     < M) bv.x = Bp[0];
          if (gc + 1 < M) bv.y = Bp[1];
          if (gc + 2 < M) bv.z = Bp[2];
        }
      }
      pb[it] = bv;
    }
  };
  auto commit = [&](int buf) {
#pragma unroll
    for (int it = 0; it < AIT; ++it) {
      const int s = it * 256 + tid;
      const int row = s >> 2, kq = (s & 3) << 2;
      As[buf][kq    ][row] = pa[it].x;
      As[buf][kq + 1][row] = pa[it].y;
      As[buf][kq + 2][row] = pa[it].z;
      As[buf][kq + 3][row] = pa[it].w;
    }
#pragma unroll
    for (int it = 0; it < BIT; ++it) {
      const int s = it * 256 + tid;
      const int kr = s / (BN / 4), c = (s % (BN / 4)) << 2;
      *(float4*)&Bs[buf][kr][c] = pb[it];
    }
  };

  load_tile(klo);
  commit(0);
  for (int t = 0; t < nt; ++t) {
    if (t + 1 < nt) load_tile(klo + (t + 1) * BK);  // global -> regs (overlaps)
    __syncthreads();  // commit(t) visible; all waves done reading buf (t+1)&1
    const int cur = t & 1;
#pragma unroll
    for (int kk = 0; kk < BK; ++kk) {
      float ar[TM], br[TN];
#pragma unroll
      for (int i = 0; i < TM; i += 4)
        *(float4*)&ar[i] = *(const float4*)&As[cur][kk][ty * TM + i];
      if constexpr (TN == 8) {
        *(float4*)&br[0] = *(const float4*)&Bs[cur][kk][tx * 4];
        *(float4*)&br[4] = *(const float4*)&Bs[cur][kk][BN / 2 + tx * 4];
      } else {
        *(float4*)&br[0] = *(const float4*)&Bs[cur][kk][tx * TN];
      }
#pragma unroll
      for (int i = 0; i < TM; ++i)
#pragma unroll
        for (int j = 0; j < TN; ++j)
          acc[i][j] += ar[i] * br[j];
    }
    if (t + 1 < nt) commit((t + 1) & 1);
  }

  float* Cz = C + (size_t)blockIdx.z * zstride;
#pragma unroll
  for (int i = 0; i < TM; ++i) {
    const int r = row0 + ty * TM + i;
    if (r >= Nr) continue;
    float* Crow = Cz + (size_t)r * ldc;
#pragma unroll
    for (int g = 0; g < TN / 4; ++g) {
      const int c = col0 + (TN == 8 ? g * (BN / 2) : 0) + tx * 4;
      if (c + 3 < M) {
        float4 v;
        v.x = acc[i][g * 4 + 0]; v.y = acc[i][g * 4 + 1];
        v.z = acc[i][g * 4 + 2]; v.w = acc[i][g * 4 + 3];
        if (bias) { v.x += bias[c]; v.y += bias[c + 1]; v.z += bias[c + 2]; v.w += bias[c + 3]; }
        if (do_relu) {
          v.x = fmaxf(v.x, 0.f); v.y = fmaxf(v.y, 0.f);
          v.z = fmaxf(v.z, 0.f); v.w = fmaxf(v.w, 0.f);
        }
        *(float4*)&Crow[c] = v;
      } else {
#pragma unroll
        for (int j = 0; j < 4; ++j) {
          if (c + j >= M) continue;
          float v = acc[i][g * 4 + j];
          if (bias) v += bias[c + j];
          if (do_relu) v = fmaxf(v, 0.f);
          Crow[c + j] = v;
        }
      }
    }
  }
}

// sum Sz split-K partials + bias (+relu), write with ldd
__global__ void bias_sum_kernel(const float* __restrict__ src, int zs, int Sz,
                                float* __restrict__ dst, int ldd,
                                const float* __restrict__ bias,
                                int Nr, int M, int do_relu) {
  int idx = blockIdx.x * blockDim.x + threadIdx.x;
  if (idx >= Nr * M) return;
  int r = idx / M, c = idx - r * M;
  float v = bias[c];
  for (int z = 0; z < Sz; ++z) v += src[idx + (size_t)z * zs];
  if (do_relu) v = fmaxf(v, 0.f);
  dst[(size_t)r * ldd + c] = v;
}

// src(512x128): rows 0..255 branch0, 256..511 branch1 -> dst[256][512] cols 0..255
__global__ void cat_kernel(const float* __restrict__ src, float* __restrict__ dst) {
  int idx = blockIdx.x * blockDim.x + threadIdx.x;
  if (idx >= 512 * 128) return;
  int r = idx >> 7, c = idx & 127;
  dst[(size_t)(r & 255) * 512 + ((r >> 8) << 7) + c] = src[idx];
}

// ------------------------- graph prep -------------------------
__global__ void hist2_kernel(const int* __restrict__ e1, const int* __restrict__ e2,
                             int* __restrict__ cnt, int E, int npass) {
  int e = blockIdx.x * blockDim.x + threadIdx.x;
  if (e < E) atomicAdd(&cnt[e1[E + e]], 1);
  else if (e < npass * E) atomicAdd(&cnt[N_NODES + e2[E + e - E]], 1);
}

// ---- 3-phase parallel exclusive scan over cnt ----
__launch_bounds__(1024)
__global__ void scan1_kernel(const int* __restrict__ cnt, int* __restrict__ row_ptr,
                             int* __restrict__ part, int n) {
  __shared__ int sh[1024];
  const int tid = threadIdx.x;
  const int i = blockIdx.x * 1024 + tid;
  const int v = (i < n) ? cnt[i] : 0;
  sh[tid] = v;
  __syncthreads();
#pragma unroll
  for (int off = 1; off < 1024; off <<= 1) {
    int t = (tid >= off) ? sh[tid - off] : 0;
    __syncthreads();
    sh[tid] += t;
    __syncthreads();
  }
  if (i < n) row_ptr[i] = sh[tid] - v;  // exclusive
  if (tid == 1023) part[blockIdx.x] = sh[tid];
}

__global__ void scan2_kernel(int* __restrict__ part, int nb) {
  if (threadIdx.x == 0 && blockIdx.x == 0) {
    int run = 0;
    for (int b = 0; b < nb; ++b) { int t = part[b]; part[b] = run; run += t; }
  }
}

__global__ void scan3_kernel(const int* __restrict__ cnt, int* __restrict__ row_ptr,
                             const int* __restrict__ part, int* __restrict__ cursor,
                             float* __restrict__ dinv, int n, int total) {
  int i = blockIdx.x * blockDim.x + threadIdx.x;
  if (i >= n) return;
  int rp = row_ptr[i] + part[i >> 10];
  row_ptr[i] = rp;
  cursor[i] = rp;
  dinv[i] = rsqrtf((float)(cnt[i] + 1));
  if (i == 0) row_ptr[n] = total;
}

__global__ void scatter2_kernel(const int* __restrict__ e1, const int* __restrict__ e2,
                                int* __restrict__ cursor, int* __restrict__ col_idx,
                                int E, int npass) {
  int e = blockIdx.x * blockDim.x + threadIdx.x;
  if (e < E) {
    int p = atomicAdd(&cursor[e1[E + e]], 1);
    col_idx[p] = e1[e];
  } else if (e < npass * E) {
    int j = e - E;
    int p = atomicAdd(&cursor[N_NODES + e2[E + j]], 1);
    col_idx[p] = N_NODES + e2[j];
  }
}

// ------------ normalized aggregation, flat (node, vec-slot) threads: 100% lanes ------------
// out = D^-1/2 (A+I) D^-1/2 x ; dual-source virtual concat for layer 1.
__global__ void aggf2_flat(const float* __restrict__ h, const float* __restrict__ h2,
                           int nsplit, const int* __restrict__ row_ptr,
                           const int* __restrict__ col_idx, const float* __restrict__ dinv,
                           float* __restrict__ out, int F, int V, int total) {
  int gid = blockIdx.x * blockDim.x + threadIdx.x;
  if (gid >= total) return;
  int n = gid / V, v = gid - n * V;
  const float din = dinv[n];
  auto rowp = [&](int s) -> const float2* {
    const float* base = (s < nsplit) ? h + (size_t)s * F : h2 + (size_t)(s - nsplit) * F;
    return (const float2*)base;
  };
  float2 a;
  { float2 x = rowp(n)[v]; a.x = din * x.x; a.y = din * x.y; }
  const int beg = row_ptr[n], end = row_ptr[n + 1];
  int e = beg;
  for (; e + 1 < end; e += 2) {
    int s0 = col_idx[e], s1 = col_idx[e + 1];
    float d0 = dinv[s0], d1 = dinv[s1];
    float2 x0 = rowp(s0)[v], x1 = rowp(s1)[v];
    a.x += d0 * x0.x + d1 * x1.x;
    a.y += d0 * x0.y + d1 * x1.y;
  }
  if (e < end) {
    int s0 = col_idx[e];
    float d0 = dinv[s0];
    float2 x0 = rowp(s0)[v];
    a.x += d0 * x0.x; a.y += d0 * x0.y;
  }
  float2 o; o.x = din * a.x; o.y = din * a.y;
  ((float2*)(out + (size_t)n * F))[v] = o;
}

__global__ void aggf4_flat(const float* __restrict__ h, const int* __restrict__ row_ptr,
                           const int* __restrict__ col_idx, const float* __restrict__ dinv,
                           float* __restrict__ out, int F, int V, int total) {
  int gid = blockIdx.x * blockDim.x + threadIdx.x;
  if (gid >= total) return;
  int n = gid / V, v = gid - n * V;
  const float din = dinv[n];
  const float4* hv = (const float4*)h;
  const int vs = F >> 2;
  float4 a;
  {
    float4 x = hv[(size_t)n * vs + v];
    a.x = din * x.x; a.y = din * x.y; a.z = din * x.z; a.w = din * x.w;
  }
  const int beg = row_ptr[n], end = row_ptr[n + 1];
  int e = beg;
  for (; e + 1 < end; e += 2) {
    int s0 = col_idx[e], s1 = col_idx[e + 1];
    float d0 = dinv[s0], d1 = dinv[s1];
    float4 x0 = hv[(size_t)s0 * vs + v], x1 = hv[(size_t)s1 * vs + v];
    a.x += d0 * x0.x + d1 * x1.x;
    a.y += d0 * x0.y + d1 * x1.y;
    a.z += d0 * x0.z + d1 * x1.z;
    a.w += d0 * x0.w + d1 * x1.w;
  }
  if (e < end) {
    int s0 = col_idx[e];
    float d0 = dinv[s0];
    float4 x0 = hv[(size_t)s0 * vs + v];
    a.x += d0 * x0.x; a.y += d0 * x0.y; a.z += d0 * x0.z; a.w += d0 * x0.w;
  }
  float4 o;
  o.x = din * a.x; o.y = din * a.y; o.z = din * a.z; o.w = din * a.w;
  ((float4*)(out + (size_t)n * F))[v] = o;
}

__global__ void starts2_kernel(const int* __restrict__ b1, const int* __restrict__ b2,
                               int* __restrict__ s1, int* __restrict__ s2, int n, int npass) {
  int i = blockIdx.x * blockDim.x + threadIdx.x;
  if (i < n) {
    if (i == 0) { s1[0] = 0; s1[N_GRAPH] = n; }
    else if (b1[i] != b1[i - 1]) s1[b1[i]] = i;
  } else if (i < npass * n) {
    int j = i - n;
    if (j == 0) { s2[0] = n; s2[N_GRAPH] = 2 * n; }
    else if (b2[j] != b2[j - 1]) s2[b2[j]] = n + j;
  }
}

__global__ void pool_kernel(const float* __restrict__ x, const int* __restrict__ s1,
                            const int* __restrict__ s2, float* __restrict__ pooled,
                            int F, int pool_base) {
  int g = blockIdx.x;
  const int* st = (g < N_GRAPH) ? s1 : s2;
  int gi = g & (N_GRAPH - 1);
  int beg = st[gi], end = st[gi + 1];
  for (int f = threadIdx.x; f < F; f += blockDim.x) {
    float m = 0.f;  // post-ReLU inputs >= 0
    for (int nn = beg; nn < end; ++nn) m = fmaxf(m, x[(size_t)nn * F + f]);
    pooled[(size_t)(pool_base + g) * F + f] = m;
  }
}

__global__ void rownorm_kernel(const float* __restrict__ cell, float* __restrict__ cv, int F) {
  int g = blockIdx.x;
  __shared__ float red[256];
  int tid = threadIdx.x;
  const float* row = cell + (size_t)g * F;
  float s = 0.f;
  for (int f = tid; f < F; f += 256) { float v = row[f]; s += v * v; }
  red[tid] = s;
  __syncthreads();
  for (int off = 128; off > 0; off >>= 1) {
    if (tid < off) red[tid] += red[tid + off];
    __syncthreads();
  }
  float inv = 1.f / fmaxf(sqrtf(red[0]), 1e-12f);
  float* orow = cv + (size_t)g * F;
  for (int f = tid; f < F; f += 256) orow[f] = row[f] * inv;
}

// ------------------------- launcher -------------------------
extern "C" void kernel_launch(void* const* d_in, const int* in_sizes, int n_in,
                              void* d_out, int out_size, void* d_ws, size_t ws_size,
                              hipStream_t stream) {
  (void)in_sizes; (void)n_in; (void)out_size;
  const float* x1  = (const float*)d_in[0];
  const int*   ei1 = (const int*)d_in[1];
  const int*   bt1 = (const int*)d_in[2];
  const float* x2  = (const float*)d_in[3];
  const int*   ei2 = (const int*)d_in[4];
  const int*   bt2 = (const int*)d_in[5];
  const float* cell = (const float*)d_in[6];
  const float* Wc1 = (const float*)d_in[7];  const float* bc1 = (const float*)d_in[8];
  const float* Wc2 = (const float*)d_in[9];  const float* bc2 = (const float*)d_in[10];
  const float* Wc3 = (const float*)d_in[11]; const float* bc3 = (const float*)d_in[12];
  const float* Wg1 = (const float*)d_in[13]; const float* bg1 = (const float*)d_in[14];
  const float* Wg2 = (const float*)d_in[15]; const float* bg2 = (const float*)d_in[16];
  const float* Wr1 = (const float*)d_in[17]; const float* br1 = (const float*)d_in[18];
  const float* Wr2 = (const float*)d_in[19]; const float* br2 = (const float*)d_in[20];
  const float* Wr3 = (const float*)d_in[21]; const float* br3 = (const float*)d_in[22];
  const float* Wf1 = (const float*)d_in[23]; const float* bf1 = (const float*)d_in[24];
  const float* Wf2 = (const float*)d_in[25]; const float* bf2 = (const float*)d_in[26];
  const float* Wf3 = (const float*)d_in[27]; const float* bf3 = (const float*)d_in[28];
  const float* Wo  = (const float*)d_in[29]; const float* bo  = (const float*)d_in[30];
  float* out = (float*)d_out;

  const bool batched = ws_size >= (size_t)95 * 1024 * 1024;
  const int NPASS = batched ? 2 : 1;
  const int NN = NPASS * N_NODES;

  char* ws = (char*)d_ws;
  size_t off = 0;
  auto alloc_f = [&](size_t ne) { float* p = (float*)(ws + off); off += ne * 4; return p; };
  auto alloc_i = [&](size_t ne) { int* p = (int*)(ws + off); off += ne * 4; return p; };
  float* xbuf   = alloc_f((size_t)NN * 312);   // activations; also aliased as split-K acc
  float* abuf   = alloc_f((size_t)NN * 156);
  float* dinv   = alloc_f(NN);
  float* pooled = alloc_f((size_t)512 * 312);
  float* cvbuf  = alloc_f((size_t)N_GRAPH * 954);
  float* gtmp1  = alloc_f((size_t)512 * 2048);
  float* gtmp2  = alloc_f((size_t)512 * 512);
  float* gtmp3  = alloc_f((size_t)N_GRAPH * 256);
  float* catbuf = alloc_f((size_t)N_GRAPH * 512);
  int* cnt     = alloc_i(NN);
  int* row_ptr = alloc_i(NN + 1);
  int* cursor  = alloc_i(NN);
  int* col_idx = alloc_i(NPASS * N_EDGES);
  int* part    = alloc_i(64);
  int* start1  = alloc_i(N_GRAPH + 1);
  int* start2  = alloc_i(N_GRAPH + 1);
  float* accb  = xbuf;  // split-K partials (MLP runs after pooling; xbuf free then)

  auto gemm_big = [&](const float* A, int lda, const float* B, int ldb, float* C, int ldc,
                      const float* bias, int Nr, int K, int M, int relu) {
    dim3 grid((M + 127) / 128, (Nr + 127) / 128, 1);
    gemm_t<128, 128, 8, 8><<<grid, 256, 0, stream>>>(A, lda, B, ldb, C, ldc, 0, bias,
                                                     Nr, K, M, relu, K);
  };
  auto gemm_med = [&](const float* A, int lda, const float* B, int ldb, float* C, int ldc,
                      const float* bias, int Nr, int K, int M, int relu) {
    dim3 grid((M + 63) / 64, (Nr + 127) / 128, 1);
    gemm_t<128, 64, 8, 4><<<grid, 256, 0, stream>>>(A, lda, B, ldb, C, ldc, 0, bias,
                                                    Nr, K, M, relu, K);
  };
  auto gemm_small = [&](const float* A, int lda, const float* B, int ldb, float* C, int ldc,
                        const float* bias, int Nr, int K, int M, int relu) {
    dim3 grid((M + 63) / 64, (Nr + 63) / 64, 1);
    gemm_t<64, 64, 4, 4><<<grid, 256, 0, stream>>>(A, lda, B, ldb, C, ldc, 0, bias,
                                                   Nr, K, M, relu, K);
  };
  // split-K MLP layer (Nr = 256): partial stores per z-slice + summing bias/act pass
  auto splitk = [&](const float* A, int lda, const float* B, int M_, int K_, int S,
                    const float* bias, float* dst, int ldd, int relu) {
    int kchunk = (((K_ + S - 1) / S) + 15) / 16 * 16;
    int Sz = (K_ + kchunk - 1) / kchunk;
    dim3 grid((M_ + 63) / 64, (N_GRAPH + 63) / 64, Sz);
    gemm_t<64, 64, 4, 4><<<grid, 256, 0, stream>>>(A, lda, B, M_, accb, M_, N_GRAPH * M_,
                                                   nullptr, N_GRAPH, K_, M_, 0, kchunk);
    int tot = N_GRAPH * M_;
    bias_sum_kernel<<<(tot + 255) / 256, 256, 0, stream>>>(accb, N_GRAPH * M_, Sz, dst, ldd,
                                                           bias, N_GRAPH, M_, relu);
  };

  auto drug_pass = [&](const float* xa, const float* xb, const int* eia, const int* eib,
                       const int* bta, const int* btb, int npass, int pool_base) {
    const int nn = npass * N_NODES;
    const int te = npass * N_EDGES;
    const int nb = (nn + 1023) / 1024;
    hipMemsetAsync(cnt, 0, nn * sizeof(int), stream);
    hist2_kernel<<<(te + 255) / 256, 256, 0, stream>>>(eia, eib, cnt, N_EDGES, npass);
    scan1_kernel<<<nb, 1024, 0, stream>>>(cnt, row_ptr, part, nn);
    scan2_kernel<<<1, 64, 0, stream>>>(part, nb);
    scan3_kernel<<<(nn + 255) / 256, 256, 0, stream>>>(cnt, row_ptr, part, cursor, dinv, nn, te);
    scatter2_kernel<<<(te + 255) / 256, 256, 0, stream>>>(eia, eib, cursor, col_idx, N_EDGES, npass);
    // layer 1: agg(78, dual-source) -> GEMM 78->78 (+bias,relu)
    {
      int tot = nn * 39;
      aggf2_flat<<<(tot + 255) / 256, 256, 0, stream>>>(xa, xb, N_NODES, row_ptr, col_idx,
                                                        dinv, abuf, 78, 39, tot);
    }
    gemm_med(abuf, 78, Wc1, 78, xbuf, 78, bc1, nn, 78, 78, 1);
    // layer 2: agg(78) -> GEMM 78->156
    {
      int tot = nn * 39;
      aggf2_flat<<<(tot + 255) / 256, 256, 0, stream>>>(xbuf, xbuf, nn, row_ptr, col_idx,
                                                        dinv, abuf, 78, 39, tot);
    }
    gemm_med(abuf, 78, Wc2, 156, xbuf, 156, bc2, nn, 78, 156, 1);
    // layer 3: agg(156) -> GEMM 156->312
    {
      int tot = nn * 39;
      aggf4_flat<<<(tot + 255) / 256, 256, 0, stream>>>(xbuf, row_ptr, col_idx,
                                                        dinv, abuf, 156, 39, tot);
    }
    gemm_big(abuf, 156, Wc3, 312, xbuf, 312, bc3, nn, 156, 312, 1);
    // pool
    starts2_kernel<<<(nn + 255) / 256, 256, 0, stream>>>(bta, btb, start1, start2, N_NODES, npass);
    pool_kernel<<<npass * N_GRAPH, 128, 0, stream>>>(xbuf, start1, start2, pooled, 312, pool_base);
  };

  if (batched) {
    drug_pass(x1, x2, ei1, ei2, bt1, bt2, 2, 0);
  } else {
    drug_pass(x1, x1, ei1, ei1, bt1, bt1, 1, 0);
    drug_pass(x2, x2, ei2, ei2, bt2, bt2, 1, N_GRAPH);
  }

  // drug head on both branches at once (512 rows; shared weights)
  gemm_med(pooled, 312, Wg1, 156, gtmp1, 156, bg1, 2 * N_GRAPH, 312, 156, 1);
  gemm_med(gtmp1, 156, Wg2, 128, gtmp2, 128, bg2, 2 * N_GRAPH, 156, 128, 0);
  cat_kernel<<<(512 * 128 + 255) / 256, 256, 0, stream>>>(gtmp2, catbuf);

  // cell branch + head MLP (256-row deep-K layers via split-K, ~1024 blocks each)
  rownorm_kernel<<<N_GRAPH, 256, 0, stream>>>(cell, cvbuf, 954);
  splitk(cvbuf, 954, Wr1, 2048, 954, 8,   br1, gtmp1, 2048, 1);
  splitk(gtmp1, 2048, Wr2, 512, 2048, 32, br2, gtmp2, 512, 1);
  splitk(gtmp2, 512, Wr3, 256, 512, 16,   br3, catbuf + 256, 512, 1);
  splitk(catbuf, 512, Wf1, 1024, 512, 16, bf1, gtmp1, 1024, 1);
  splitk(gtmp1, 1024, Wf2, 512, 1024, 32, bf2, gtmp2, 512, 1);
  splitk(gtmp2, 512, Wf3, 128, 512, 32,   bf3, gtmp3, 128, 1);
  gemm_small(gtmp3, 128, Wo, 2, out, 2, bo, N_GRAPH, 128, 2, 0);
}

// Round 7
// 699.882 us; speedup vs baseline: 1.1159x; 1.1159x over previous
//
#include <hip/hip_runtime.h>

#define N_NODES 20000
#define N_EDGES 320000
#define N_GRAPH 256

// ------------------------- templated tiled fp32 GEMM -------------------------
// zstride==0: direct C = op(A@B + bias). zstride>0 (split-K): block z plain-stores
// its partial to C + z*zstride (summed later by bias_sum_kernel).
// A-tile k-major in LDS; B-fragment split in two stride-4 groups (2-way = free).
// Single LDS buffer + register prefetch of tile k+1 (R5 structure: VGPR~100;
// the 2-deep LDS double buffer variant was measured SLOWER: VGPR 188, occ 10%).
template<int BM, int BN, int TM, int TN>
__launch_bounds__(256)
__global__ void gemm_t(const float* __restrict__ A, int lda,
                       const float* __restrict__ B, int ldb,
                       float* __restrict__ C, int ldc, int zstride,
                       const float* __restrict__ bias,
                       int Nr, int K, int M, int do_relu, int kchunk) {
  constexpr int BK = 16;
  constexpr int LDA = BM + 4;
  __shared__ __align__(16) float As[BK][LDA];
  __shared__ __align__(16) float Bs[BK][BN];
  const int tid = threadIdx.x;
  const int row0 = blockIdx.y * BM, col0 = blockIdx.x * BN;
  constexpr int NX = BN / TN;
  const int tx = tid % NX, ty = tid / NX;
  float acc[TM][TN] = {};
  const int klo = blockIdx.z * kchunk;
  const int khi = min(klo + kchunk, K);

  constexpr int AIT = BM * BK / 4 / 256;
  constexpr int BIT = BK * BN / 4 / 256;
  float4 pa[AIT], pb[BIT];

  auto load_tile = [&](int k0) {
#pragma unroll
    for (int it = 0; it < AIT; ++it) {
      const int s = it * 256 + tid;
      const int row = s >> 2, kq = (s & 3) << 2;
      float4 av = make_float4(0.f, 0.f, 0.f, 0.f);
      const int gr = row0 + row, gk = k0 + kq;
      if (gr < Nr) {
        const float* Ap = A + (size_t)gr * lda + gk;
        if (gk + 3 < khi) { av.x = Ap[0]; av.y = Ap[1]; av.z = Ap[2]; av.w = Ap[3]; }
        else {
          if (gk     < khi) av.x = Ap[0];
          if (gk + 1 < khi) av.y = Ap[1];
          if (gk + 2 < khi) av.z = Ap[2];
        }
      }
      pa[it] = av;
    }
#pragma unroll
    for (int it = 0; it < BIT; ++it) {
      const int s = it * 256 + tid;
      const int kr = s / (BN / 4), c = (s % (BN / 4)) << 2;
      float4 bv = make_float4(0.f, 0.f, 0.f, 0.f);
      const int gk = k0 + kr, gc = col0 + c;
      if (gk < khi) {
        const float* Bp = B + (size_t)gk * ldb + gc;
        if (gc + 3 < M) { bv.x = Bp[0]; bv.y = Bp[1]; bv.z = Bp[2]; bv.w = Bp[3]; }
        else {
          if (gc     < M) bv.x = Bp[0];
          if (gc + 1 < M) bv.y = Bp[1];
          if (gc + 2 < M) bv.z = Bp[2];
        }
      }
      pb[it] = bv;
    }
  };

  load_tile(klo);
  for (int k0 = klo; k0 < khi; k0 += BK) {
#pragma unroll
    for (int it = 0; it < AIT; ++it) {
      const int s = it * 256 + tid;
      const int row = s >> 2, kq = (s & 3) << 2;
      As[kq    ][row] = pa[it].x;
      As[kq + 1][row] = pa[it].y;
      As[kq + 2][row] = pa[it].z;
      As[kq + 3][row] = pa[it].w;
    }
#pragma unroll
    for (int it = 0; it < BIT; ++it) {
      const int s = it * 256 + tid;
      const int kr = s / (BN / 4), c = (s % (BN / 4)) << 2;
      *(float4*)&Bs[kr][c] = pb[it];
    }
    __syncthreads();
    if (k0 + BK < khi) load_tile(k0 + BK);  // overlap next-tile fetch with compute
#pragma unroll
    for (int kk = 0; kk < BK; ++kk) {
      float ar[TM], br[TN];
#pragma unroll
      for (int i = 0; i < TM; i += 4)
        *(float4*)&ar[i] = *(const float4*)&As[kk][ty * TM + i];
      if constexpr (TN == 8) {
        *(float4*)&br[0] = *(const float4*)&Bs[kk][tx * 4];
        *(float4*)&br[4] = *(const float4*)&Bs[kk][BN / 2 + tx * 4];
      } else {
        *(float4*)&br[0] = *(const float4*)&Bs[kk][tx * TN];
      }
#pragma unroll
      for (int i = 0; i < TM; ++i)
#pragma unroll
        for (int j = 0; j < TN; ++j)
          acc[i][j] += ar[i] * br[j];
    }
    __syncthreads();
  }

  float* Cz = C + (size_t)blockIdx.z * zstride;
#pragma unroll
  for (int i = 0; i < TM; ++i) {
    const int r = row0 + ty * TM + i;
    if (r >= Nr) continue;
    float* Crow = Cz + (size_t)r * ldc;
#pragma unroll
    for (int g = 0; g < TN / 4; ++g) {
      const int c = col0 + (TN == 8 ? g * (BN / 2) : 0) + tx * 4;
      if (c + 3 < M) {
        float4 v;
        v.x = acc[i][g * 4 + 0]; v.y = acc[i][g * 4 + 1];
        v.z = acc[i][g * 4 + 2]; v.w = acc[i][g * 4 + 3];
        if (bias) { v.x += bias[c]; v.y += bias[c + 1]; v.z += bias[c + 2]; v.w += bias[c + 3]; }
        if (do_relu) {
          v.x = fmaxf(v.x, 0.f); v.y = fmaxf(v.y, 0.f);
          v.z = fmaxf(v.z, 0.f); v.w = fmaxf(v.w, 0.f);
        }
        *(float4*)&Crow[c] = v;
      } else {
#pragma unroll
        for (int j = 0; j < 4; ++j) {
          if (c + j >= M) continue;
          float v = acc[i][g * 4 + j];
          if (bias) v += bias[c + j];
          if (do_relu) v = fmaxf(v, 0.f);
          Crow[c + j] = v;
        }
      }
    }
  }
}

// sum Sz split-K partials + bias (+relu), write with ldd
__global__ void bias_sum_kernel(const float* __restrict__ src, int zs, int Sz,
                                float* __restrict__ dst, int ldd,
                                const float* __restrict__ bias,
                                int Nr, int M, int do_relu) {
  int idx = blockIdx.x * blockDim.x + threadIdx.x;
  if (idx >= Nr * M) return;
  int r = idx / M, c = idx - r * M;
  float v = bias[c];
  for (int z = 0; z < Sz; ++z) v += src[idx + (size_t)z * zs];
  if (do_relu) v = fmaxf(v, 0.f);
  dst[(size_t)r * ldd + c] = v;
}

// src(512x128): rows 0..255 branch0, 256..511 branch1 -> dst[256][512] cols 0..255
__global__ void cat_kernel(const float* __restrict__ src, float* __restrict__ dst) {
  int idx = blockIdx.x * blockDim.x + threadIdx.x;
  if (idx >= 512 * 128) return;
  int r = idx >> 7, c = idx & 127;
  dst[(size_t)(r & 255) * 512 + ((r >> 8) << 7) + c] = src[idx];
}

// ------------------------- graph prep -------------------------
__global__ void hist2_kernel(const int* __restrict__ e1, const int* __restrict__ e2,
                             int* __restrict__ cnt, int E, int npass) {
  int e = blockIdx.x * blockDim.x + threadIdx.x;
  if (e < E) atomicAdd(&cnt[e1[E + e]], 1);
  else if (e < npass * E) atomicAdd(&cnt[N_NODES + e2[E + e - E]], 1);
}

// ---- 3-phase parallel exclusive scan over cnt ----
__launch_bounds__(1024)
__global__ void scan1_kernel(const int* __restrict__ cnt, int* __restrict__ row_ptr,
                             int* __restrict__ part, int n) {
  __shared__ int sh[1024];
  const int tid = threadIdx.x;
  const int i = blockIdx.x * 1024 + tid;
  const int v = (i < n) ? cnt[i] : 0;
  sh[tid] = v;
  __syncthreads();
#pragma unroll
  for (int off = 1; off < 1024; off <<= 1) {
    int t = (tid >= off) ? sh[tid - off] : 0;
    __syncthreads();
    sh[tid] += t;
    __syncthreads();
  }
  if (i < n) row_ptr[i] = sh[tid] - v;  // exclusive
  if (tid == 1023) part[blockIdx.x] = sh[tid];
}

__global__ void scan2_kernel(int* __restrict__ part, int nb) {
  if (threadIdx.x == 0 && blockIdx.x == 0) {
    int run = 0;
    for (int b = 0; b < nb; ++b) { int t = part[b]; part[b] = run; run += t; }
  }
}

__global__ void scan3_kernel(const int* __restrict__ cnt, int* __restrict__ row_ptr,
                             const int* __restrict__ part, int* __restrict__ cursor,
                             float* __restrict__ dinv, int n, int total) {
  int i = blockIdx.x * blockDim.x + threadIdx.x;
  if (i >= n) return;
  int rp = row_ptr[i] + part[i >> 10];
  row_ptr[i] = rp;
  cursor[i] = rp;
  dinv[i] = rsqrtf((float)(cnt[i] + 1));
  if (i == 0) row_ptr[n] = total;
}

__global__ void scatter2_kernel(const int* __restrict__ e1, const int* __restrict__ e2,
                                int* __restrict__ cursor, int* __restrict__ col_idx,
                                int E, int npass) {
  int e = blockIdx.x * blockDim.x + threadIdx.x;
  if (e < E) {
    int p = atomicAdd(&cursor[e1[E + e]], 1);
    col_idx[p] = e1[e];
  } else if (e < npass * E) {
    int j = e - E;
    int p = atomicAdd(&cursor[N_NODES + e2[E + j]], 1);
    col_idx[p] = N_NODES + e2[j];
  }
}

// ------------ normalized aggregation, flat (node, vec-slot) threads: 100% lanes ------------
// out = D^-1/2 (A+I) D^-1/2 x ; dual-source virtual concat for layer 1.
__global__ void aggf2_flat(const float* __restrict__ h, const float* __restrict__ h2,
                           int nsplit, const int* __restrict__ row_ptr,
                           const int* __restrict__ col_idx, const float* __restrict__ dinv,
                           float* __restrict__ out, int F, int V, int total) {
  int gid = blockIdx.x * blockDim.x + threadIdx.x;
  if (gid >= total) return;
  int n = gid / V, v = gid - n * V;
  const float din = dinv[n];
  auto rowp = [&](int s) -> const float2* {
    const float* base = (s < nsplit) ? h + (size_t)s * F : h2 + (size_t)(s - nsplit) * F;
    return (const float2*)base;
  };
  float2 a;
  { float2 x = rowp(n)[v]; a.x = din * x.x; a.y = din * x.y; }
  const int beg = row_ptr[n], end = row_ptr[n + 1];
  int e = beg;
  for (; e + 1 < end; e += 2) {
    int s0 = col_idx[e], s1 = col_idx[e + 1];
    float d0 = dinv[s0], d1 = dinv[s1];
    float2 x0 = rowp(s0)[v], x1 = rowp(s1)[v];
    a.x += d0 * x0.x + d1 * x1.x;
    a.y += d0 * x0.y + d1 * x1.y;
  }
  if (e < end) {
    int s0 = col_idx[e];
    float d0 = dinv[s0];
    float2 x0 = rowp(s0)[v];
    a.x += d0 * x0.x; a.y += d0 * x0.y;
  }
  float2 o; o.x = din * a.x; o.y = din * a.y;
  ((float2*)(out + (size_t)n * F))[v] = o;
}

__global__ void aggf4_flat(const float* __restrict__ h, const int* __restrict__ row_ptr,
                           const int* __restrict__ col_idx, const float* __restrict__ dinv,
                           float* __restrict__ out, int F, int V, int total) {
  int gid = blockIdx.x * blockDim.x + threadIdx.x;
  if (gid >= total) return;
  int n = gid / V, v = gid - n * V;
  const float din = dinv[n];
  const float4* hv = (const float4*)h;
  const int vs = F >> 2;
  float4 a;
  {
    float4 x = hv[(size_t)n * vs + v];
    a.x = din * x.x; a.y = din * x.y; a.z = din * x.z; a.w = din * x.w;
  }
  const int beg = row_ptr[n], end = row_ptr[n + 1];
  int e = beg;
  for (; e + 1 < end; e += 2) {
    int s0 = col_idx[e], s1 = col_idx[e + 1];
    float d0 = dinv[s0], d1 = dinv[s1];
    float4 x0 = hv[(size_t)s0 * vs + v], x1 = hv[(size_t)s1 * vs + v];
    a.x += d0 * x0.x + d1 * x1.x;
    a.y += d0 * x0.y + d1 * x1.y;
    a.z += d0 * x0.z + d1 * x1.z;
    a.w += d0 * x0.w + d1 * x1.w;
  }
  if (e < end) {
    int s0 = col_idx[e];
    float d0 = dinv[s0];
    float4 x0 = hv[(size_t)s0 * vs + v];
    a.x += d0 * x0.x; a.y += d0 * x0.y; a.z += d0 * x0.z; a.w += d0 * x0.w;
  }
  float4 o;
  o.x = din * a.x; o.y = din * a.y; o.z = din * a.z; o.w = din * a.w;
  ((float4*)(out + (size_t)n * F))[v] = o;
}

__global__ void starts2_kernel(const int* __restrict__ b1, const int* __restrict__ b2,
                               int* __restrict__ s1, int* __restrict__ s2, int n, int npass) {
  int i = blockIdx.x * blockDim.x + threadIdx.x;
  if (i < n) {
    if (i == 0) { s1[0] = 0; s1[N_GRAPH] = n; }
    else if (b1[i] != b1[i - 1]) s1[b1[i]] = i;
  } else if (i < npass * n) {
    int j = i - n;
    if (j == 0) { s2[0] = n; s2[N_GRAPH] = 2 * n; }
    else if (b2[j] != b2[j - 1]) s2[b2[j]] = n + j;
  }
}

__global__ void pool_kernel(const float* __restrict__ x, const int* __restrict__ s1,
                            const int* __restrict__ s2, float* __restrict__ pooled,
                            int F, int pool_base) {
  int g = blockIdx.x;
  const int* st = (g < N_GRAPH) ? s1 : s2;
  int gi = g & (N_GRAPH - 1);
  int beg = st[gi], end = st[gi + 1];
  for (int f = threadIdx.x; f < F; f += blockDim.x) {
    float m = 0.f;  // post-ReLU inputs >= 0
    for (int nn = beg; nn < end; ++nn) m = fmaxf(m, x[(size_t)nn * F + f]);
    pooled[(size_t)(pool_base + g) * F + f] = m;
  }
}

__global__ void rownorm_kernel(const float* __restrict__ cell, float* __restrict__ cv, int F) {
  int g = blockIdx.x;
  __shared__ float red[256];
  int tid = threadIdx.x;
  const float* row = cell + (size_t)g * F;
  float s = 0.f;
  for (int f = tid; f < F; f += 256) { float v = row[f]; s += v * v; }
  red[tid] = s;
  __syncthreads();
  for (int off = 128; off > 0; off >>= 1) {
    if (tid < off) red[tid] += red[tid + off];
    __syncthreads();
  }
  float inv = 1.f / fmaxf(sqrtf(red[0]), 1e-12f);
  float* orow = cv + (size_t)g * F;
  for (int f = tid; f < F; f += 256) orow[f] = row[f] * inv;
}

// ------------------------- launcher -------------------------
extern "C" void kernel_launch(void* const* d_in, const int* in_sizes, int n_in,
                              void* d_out, int out_size, void* d_ws, size_t ws_size,
                              hipStream_t stream) {
  (void)in_sizes; (void)n_in; (void)out_size;
  const float* x1  = (const float*)d_in[0];
  const int*   ei1 = (const int*)d_in[1];
  const int*   bt1 = (const int*)d_in[2];
  const float* x2  = (const float*)d_in[3];
  const int*   ei2 = (const int*)d_in[4];
  const int*   bt2 = (const int*)d_in[5];
  const float* cell = (const float*)d_in[6];
  const float* Wc1 = (const float*)d_in[7];  const float* bc1 = (const float*)d_in[8];
  const float* Wc2 = (const float*)d_in[9];  const float* bc2 = (const float*)d_in[10];
  const float* Wc3 = (const float*)d_in[11]; const float* bc3 = (const float*)d_in[12];
  const float* Wg1 = (const float*)d_in[13]; const float* bg1 = (const float*)d_in[14];
  const float* Wg2 = (const float*)d_in[15]; const float* bg2 = (const float*)d_in[16];
  const float* Wr1 = (const float*)d_in[17]; const float* br1 = (const float*)d_in[18];
  const float* Wr2 = (const float*)d_in[19]; const float* br2 = (const float*)d_in[20];
  const float* Wr3 = (const float*)d_in[21]; const float* br3 = (const float*)d_in[22];
  const float* Wf1 = (const float*)d_in[23]; const float* bf1 = (const float*)d_in[24];
  const float* Wf2 = (const float*)d_in[25]; const float* bf2 = (const float*)d_in[26];
  const float* Wf3 = (const float*)d_in[27]; const float* bf3 = (const float*)d_in[28];
  const float* Wo  = (const float*)d_in[29]; const float* bo  = (const float*)d_in[30];
  float* out = (float*)d_out;

  const bool batched = ws_size >= (size_t)95 * 1024 * 1024;
  const int NPASS = batched ? 2 : 1;
  const int NN = NPASS * N_NODES;

  char* ws = (char*)d_ws;
  size_t off = 0;
  auto alloc_f = [&](size_t ne) { float* p = (float*)(ws + off); off += ne * 4; return p; };
  auto alloc_i = [&](size_t ne) { int* p = (int*)(ws + off); off += ne * 4; return p; };
  float* xbuf   = alloc_f((size_t)NN * 312);   // activations; also aliased as split-K acc
  float* abuf   = alloc_f((size_t)NN * 156);
  float* dinv   = alloc_f(NN);
  float* pooled = alloc_f((size_t)512 * 312);
  float* cvbuf  = alloc_f((size_t)N_GRAPH * 954);
  float* gtmp1  = alloc_f((size_t)512 * 2048);
  float* gtmp2  = alloc_f((size_t)512 * 512);
  float* gtmp3  = alloc_f((size_t)N_GRAPH * 256);
  float* catbuf = alloc_f((size_t)N_GRAPH * 512);
  int* cnt     = alloc_i(NN);
  int* row_ptr = alloc_i(NN + 1);
  int* cursor  = alloc_i(NN);
  int* col_idx = alloc_i(NPASS * N_EDGES);
  int* part    = alloc_i(64);
  int* start1  = alloc_i(N_GRAPH + 1);
  int* start2  = alloc_i(N_GRAPH + 1);
  float* accb  = xbuf;  // split-K partials (MLP runs after pooling; xbuf free then)

  auto gemm_big = [&](const float* A, int lda, const float* B, int ldb, float* C, int ldc,
                      const float* bias, int Nr, int K, int M, int relu) {
    dim3 grid((M + 127) / 128, (Nr + 127) / 128, 1);
    gemm_t<128, 128, 8, 8><<<grid, 256, 0, stream>>>(A, lda, B, ldb, C, ldc, 0, bias,
                                                     Nr, K, M, relu, K);
  };
  auto gemm_med = [&](const float* A, int lda, const float* B, int ldb, float* C, int ldc,
                      const float* bias, int Nr, int K, int M, int relu) {
    dim3 grid((M + 63) / 64, (Nr + 127) / 128, 1);
    gemm_t<128, 64, 8, 4><<<grid, 256, 0, stream>>>(A, lda, B, ldb, C, ldc, 0, bias,
                                                    Nr, K, M, relu, K);
  };
  auto gemm_small = [&](const float* A, int lda, const float* B, int ldb, float* C, int ldc,
                        const float* bias, int Nr, int K, int M, int relu) {
    dim3 grid((M + 63) / 64, (Nr + 63) / 64, 1);
    gemm_t<64, 64, 4, 4><<<grid, 256, 0, stream>>>(A, lda, B, ldb, C, ldc, 0, bias,
                                                   Nr, K, M, relu, K);
  };
  // split-K MLP layer (Nr = 256): partial stores per z-slice + summing bias/act pass
  auto splitk = [&](const float* A, int lda, const float* B, int M_, int K_, int S,
                    const float* bias, float* dst, int ldd, int relu) {
    int kchunk = (((K_ + S - 1) / S) + 15) / 16 * 16;
    int Sz = (K_ + kchunk - 1) / kchunk;
    dim3 grid((M_ + 63) / 64, (N_GRAPH + 63) / 64, Sz);
    gemm_t<64, 64, 4, 4><<<grid, 256, 0, stream>>>(A, lda, B, M_, accb, M_, N_GRAPH * M_,
                                                   nullptr, N_GRAPH, K_, M_, 0, kchunk);
    int tot = N_GRAPH * M_;
    bias_sum_kernel<<<(tot + 255) / 256, 256, 0, stream>>>(accb, N_GRAPH * M_, Sz, dst, ldd,
                                                           bias, N_GRAPH, M_, relu);
  };

  auto drug_pass = [&](const float* xa, const float* xb, const int* eia, const int* eib,
                       const int* bta, const int* btb, int npass, int pool_base) {
    const int nn = npass * N_NODES;
    const int te = npass * N_EDGES;
    const int nb = (nn + 1023) / 1024;
    hipMemsetAsync(cnt, 0, nn * sizeof(int), stream);
    hist2_kernel<<<(te + 255) / 256, 256, 0, stream>>>(eia, eib, cnt, N_EDGES, npass);
    scan1_kernel<<<nb, 1024, 0, stream>>>(cnt, row_ptr, part, nn);
    scan2_kernel<<<1, 64, 0, stream>>>(part, nb);
    scan3_kernel<<<(nn + 255) / 256, 256, 0, stream>>>(cnt, row_ptr, part, cursor, dinv, nn, te);
    scatter2_kernel<<<(te + 255) / 256, 256, 0, stream>>>(eia, eib, cursor, col_idx, N_EDGES, npass);
    // layer 1: agg(78, dual-source) -> GEMM 78->78 (+bias,relu)
    {
      int tot = nn * 39;
      aggf2_flat<<<(tot + 255) / 256, 256, 0, stream>>>(xa, xb, N_NODES, row_ptr, col_idx,
                                                        dinv, abuf, 78, 39, tot);
    }
    gemm_med(abuf, 78, Wc1, 78, xbuf, 78, bc1, nn, 78, 78, 1);
    // layer 2: agg(78) -> GEMM 78->156
    {
      int tot = nn * 39;
      aggf2_flat<<<(tot + 255) / 256, 256, 0, stream>>>(xbuf, xbuf, nn, row_ptr, col_idx,
                                                        dinv, abuf, 78, 39, tot);
    }
    gemm_med(abuf, 78, Wc2, 156, xbuf, 156, bc2, nn, 78, 156, 1);
    // layer 3: agg(156) -> GEMM 156->312
    {
      int tot = nn * 39;
      aggf4_flat<<<(tot + 255) / 256, 256, 0, stream>>>(xbuf, row_ptr, col_idx,
                                                        dinv, abuf, 156, 39, tot);
    }
    gemm_big(abuf, 156, Wc3, 312, xbuf, 312, bc3, nn, 156, 312, 1);
    // pool
    starts2_kernel<<<(nn + 255) / 256, 256, 0, stream>>>(bta, btb, start1, start2, N_NODES, npass);
    pool_kernel<<<npass * N_GRAPH, 128, 0, stream>>>(xbuf, start1, start2, pooled, 312, pool_base);
  };

  if (batched) {
    drug_pass(x1, x2, ei1, ei2, bt1, bt2, 2, 0);
  } else {
    drug_pass(x1, x1, ei1, ei1, bt1, bt1, 1, 0);
    drug_pass(x2, x2, ei2, ei2, bt2, bt2, 1, N_GRAPH);
  }

  // drug head on both branches at once (512 rows; shared weights)
  gemm_med(pooled, 312, Wg1, 156, gtmp1, 156, bg1, 2 * N_GRAPH, 312, 156, 1);
  gemm_med(gtmp1, 156, Wg2, 128, gtmp2, 128, bg2, 2 * N_GRAPH, 156, 128, 0);
  cat_kernel<<<(512 * 128 + 255) / 256, 256, 0, stream>>>(gtmp2, catbuf);

  // cell branch + head MLP (256-row deep-K layers via split-K, ~1024 blocks each)
  rownorm_kernel<<<N_GRAPH, 256, 0, stream>>>(cell, cvbuf, 954);
  splitk(cvbuf, 954, Wr1, 2048, 954, 8,   br1, gtmp1, 2048, 1);
  splitk(gtmp1, 2048, Wr2, 512, 2048, 32, br2, gtmp2, 512, 1);
  splitk(gtmp2, 512, Wr3, 256, 512, 16,   br3, catbuf + 256, 512, 1);
  splitk(catbuf, 512, Wf1, 1024, 512, 16, bf1, gtmp1, 1024, 1);
  splitk(gtmp1, 1024, Wf2, 512, 1024, 32, bf2, gtmp2, 512, 1);
  splitk(gtmp2, 512, Wf3, 128, 512, 32,   bf3, gtmp3, 128, 1);
  gemm_small(gtmp3, 128, Wo, 2, out, 2, bo, N_GRAPH, 128, 2, 0);
}